// Round 6
// baseline (802.757 us; speedup 1.0000x reference)
//
#include <hip/hip_runtime.h>
#include <hip/hip_bf16.h>
#include <math.h>

#define G 4
#define S 2048
#define MDIM 1024
#define E 8
#define HDIM 4096
#define TOPK 2
#define CAP 640
#define GC (G*CAP)      /* 2560 rows per expert */

typedef __attribute__((ext_vector_type(8))) short bf16x8;
typedef __attribute__((ext_vector_type(4))) short s16x4;
typedef __attribute__((ext_vector_type(4))) float f32x4;
typedef unsigned int u32;
typedef unsigned short u16;

#define MFMA16(a,b,c) __builtin_amdgcn_mfma_f32_16x16x32_bf16(a,b,c,0,0,0)

__device__ __forceinline__ u16 f2bf(float f) {
    union { float f; u32 u; } v; v.f = f;
    u32 r = v.u + 0x7fffu + ((v.u >> 16) & 1u);
    return (u16)(r >> 16);
}

__device__ __forceinline__ void gload16(const char* gp, char* lp) {
    __builtin_amdgcn_global_load_lds((const __attribute__((address_space(1))) u32*)gp,
                                     (__attribute__((address_space(3))) u32*)lp,
                                     16, 0, 0);
}

// swizzle for 64-byte LDS rows (XOR involution, applied to global src + LDS read)
__device__ __forceinline__ int swzb(int r) { return ((r >> 1) & 3) << 4; }

// ---------------- weight transpose + f32->bf16 convert (64x64, R5-proven) ----
// in: [E][R][C] f32   out: [E][C][R] bf16
__global__ __launch_bounds__(256) void transpose_cvt(const float* __restrict__ in,
                                                     u16* __restrict__ out, int R, int C) {
    int e = blockIdx.z;
    const float* ine = in + (size_t)e * R * C;
    u16* oute = out + (size_t)e * R * C;
    __shared__ float tile[64][68];
    int t = threadIdx.x;
    int x0 = blockIdx.x * 64, y0 = blockIdx.y * 64;
    int lx = (t & 15) * 4, ly = t >> 4;
    #pragma unroll
    for (int i = 0; i < 4; ++i) {
        f32x4 v = *(const f32x4*)(ine + (size_t)(y0 + ly + i * 16) * C + x0 + lx);
        *(f32x4*)&tile[ly + i * 16][lx] = v;
    }
    __syncthreads();
    int rr0 = (t & 15) * 4, cb = t >> 4;
    #pragma unroll
    for (int p = 0; p < 4; ++p) {
        int cc = cb + p * 16;
        s16x4 pk;
        #pragma unroll
        for (int j = 0; j < 4; ++j) pk[j] = (short)f2bf(tile[rr0 + j][cc]);
        *(s16x4*)(oute + (size_t)(x0 + cc) * R + y0 + rr0) = pk;
    }
}

// ---------------- router ----------------
__global__ __launch_bounds__(256) void router_kernel(const float* __restrict__ inp,
                                                     const float* __restrict__ rw,
                                                     int* __restrict__ top_i,
                                                     float* __restrict__ top_p,
                                                     float* __restrict__ partials) {
    int wid = threadIdx.x >> 6, lane = threadIdx.x & 63;
    int tok = blockIdx.x * 4 + wid;
    const float* x = inp + (size_t)tok * MDIM;
    float acc[E] = {0.f,0.f,0.f,0.f,0.f,0.f,0.f,0.f};
    #pragma unroll
    for (int rep = 0; rep < 4; ++rep) {
        int m0 = rep * 256 + lane * 4;
        f32x4 xv = *(const f32x4*)(x + m0);
        #pragma unroll
        for (int j = 0; j < 4; ++j) {
            const float* r = rw + (size_t)(m0 + j) * E;
            float xj = xv[j];
            #pragma unroll
            for (int e = 0; e < E; ++e) acc[e] += xj * r[e];
        }
    }
    #pragma unroll
    for (int e = 0; e < E; ++e)
        #pragma unroll
        for (int off = 32; off; off >>= 1) acc[e] += __shfl_down(acc[e], off);

    __shared__ float part[4][17];
    if (lane == 0) {
        float mx = acc[0];
        #pragma unroll
        for (int e = 1; e < E; ++e) mx = fmaxf(mx, acc[e]);
        float p[E], sum = 0.f;
        #pragma unroll
        for (int e = 0; e < E; ++e) { p[e] = expf(acc[e] - mx); sum += p[e]; }
        float inv = 1.f / sum;
        #pragma unroll
        for (int e = 0; e < E; ++e) p[e] *= inv;
        float lse = logf(sum) + mx;
        int i0 = 0;
        #pragma unroll
        for (int e = 1; e < E; ++e) if (acc[e] > acc[i0]) i0 = e;
        int i1 = (i0 == 0) ? 1 : 0;
        #pragma unroll
        for (int e = 0; e < E; ++e) if (e != i0 && acc[e] > acc[i1]) i1 = e;
        top_i[tok*2+0] = i0; top_i[tok*2+1] = i1;
        top_p[tok*2+0] = p[i0]; top_p[tok*2+1] = p[i1];
        #pragma unroll
        for (int e = 0; e < E; ++e) { part[wid][e] = p[e]; part[wid][8+e] = 0.f; }
        part[wid][8+i0] = 1.f; part[wid][8+i1] = 1.f;
        part[wid][16] = lse * lse;
    }
    __syncthreads();
    if (threadIdx.x < 17) {
        float v = part[0][threadIdx.x] + part[1][threadIdx.x] +
                  part[2][threadIdx.x] + part[3][threadIdx.x];
        partials[(size_t)blockIdx.x * 17 + threadIdx.x] = v;
    }
}

__global__ __launch_bounds__(256) void reduce_partials(const float* __restrict__ partials,
                                                       float* __restrict__ sums) {
    int g = blockIdx.x, t = threadIdx.x;
    float loc[17];
    #pragma unroll
    for (int c = 0; c < 17; ++c) loc[c] = 0.f;
    for (int r = t; r < 1024; r += 256) {
        const float* pr = partials + ((size_t)g * 1024 + r) * 17;
        #pragma unroll
        for (int c = 0; c < 17; ++c) loc[c] += pr[c];
    }
    __shared__ float red[256];
    for (int c = 0; c < 17; ++c) {
        red[t] = loc[c]; __syncthreads();
        for (int off = 128; off; off >>= 1) {
            if (t < off) red[t] += red[t + off];
            __syncthreads();
        }
        if (t == 0) sums[g * 17 + c] = red[0];
        __syncthreads();
    }
}

__global__ void aux_final(const float* __restrict__ sums, float* __restrict__ out) {
    float lb = 0.f, z = 0.f;
    for (int g = 0; g < G; ++g) {
        for (int e = 0; e < E; ++e)
            lb += (sums[g*17 + 8 + e] / (float)S) * (sums[g*17 + e] / (float)S);
        z += sums[g*17 + 16];
    }
    lb = lb / (float)(G * E) * (float)(E * E);
    z /= (float)(G * S);
    out[(size_t)G * S * MDIM] = 0.01f * lb + 0.001f * z;
}

// ---------------- capacity scan ----------------
__global__ __launch_bounds__(256) void scan_kernel(const int* __restrict__ top_i,
                                                   const float* __restrict__ pad,
                                                   int* __restrict__ slot_token,
                                                   int* __restrict__ token_c) {
    int b = blockIdx.x; int g = b >> 3, e = b & 7;
    int t = threadIdx.x;
    __shared__ int sums[256];
    int base = t * 16;
    int run = 0; unsigned mask16 = 0; int loc[16];
    #pragma unroll
    for (int j = 0; j < 16; ++j) {
        int i = base + j; int s = i >> 1, k = i & 1;
        int ex = top_i[((size_t)(g * S + s)) * 2 + k];
        int m = (ex == e) && (pad[g * S + s] == 0.f);
        run += m; loc[j] = run; mask16 |= ((unsigned)m << j);
    }
    sums[t] = run; __syncthreads();
    for (int off = 1; off < 256; off <<= 1) {
        int v = (t >= off) ? sums[t - off] : 0;
        __syncthreads();
        sums[t] += v;
        __syncthreads();
    }
    int excl = sums[t] - run;
    #pragma unroll
    for (int j = 0; j < 16; ++j) {
        if ((mask16 >> j) & 1u) {
            int pos = excl + loc[j];
            if (pos <= CAP) {
                int i = base + j; int s = i >> 1, k = i & 1;
                slot_token[((size_t)(e * G + g)) * CAP + (pos - 1)] = s;
                token_c[((size_t)(g * S + s)) * 2 + k] = pos - 1;
            }
        }
    }
}

// ---------------- gather tokens -> X bf16 [E][GC][MDIM] ----------------
__global__ __launch_bounds__(128) void gather_kernel(const float* __restrict__ inp,
                                                     const int* __restrict__ slot_token,
                                                     u16* __restrict__ X) {
    int row = blockIdx.x;
    int t = threadIdx.x;
    int s = slot_token[row];
    int g = (row % GC) / CAP;
    bf16x8 v;
    if (s >= 0) {
        const float* src = inp + ((size_t)(g * S + s)) * MDIM + t * 8;
        f32x4 a = *(const f32x4*)src;
        f32x4 b = *(const f32x4*)(src + 4);
        #pragma unroll
        for (int j = 0; j < 4; ++j) { v[j] = (short)f2bf(a[j]); v[4+j] = (short)f2bf(b[j]); }
    } else {
        #pragma unroll
        for (int j = 0; j < 8; ++j) v[j] = 0;
    }
    *(bf16x8*)(X + (size_t)row * MDIM + t * 8) = v;
}

// ======================================================================
// GEMM1+2 fused: BM=128 BN=128 BK=32, 256 threads (4 waves, 2Mx2N),
// wave tile 64x64 per B (dual), ring-2 LDS 48KB -> 2 blocks/CU so one
// block's LDS-read burst overlaps the other block's MFMA burst (m114).
// Body = minimal 2-phase: stage(t+1) -> ds_read(t) -> MFMA -> vmcnt(0)
// -> s_barrier. LDS half: A 8KB @0, Bg 8KB @8192, B0 8KB @16384.
// ======================================================================
__global__ __launch_bounds__(256, 2) void gemm_ffn12_v6(
        const u16* __restrict__ Xb, const u16* __restrict__ WgT,
        const u16* __restrict__ W0T, u16* __restrict__ Hb) {
    extern __shared__ char smem[];
    const int NK = MDIM / 32;                      // 32
    int bid = blockIdx.x;
    int swz = (bid & 7) * 640 + (bid >> 3);        // bijective (5120 % 8 == 0)
    int mt = swz % 20, nt = (swz / 20) % 32, e = swz / 640;
    const char* A  = (const char*)(Xb  + (size_t)e * GC * MDIM   + (size_t)mt * 128 * MDIM);
    const char* Bg = (const char*)(WgT + (size_t)e * HDIM * MDIM + (size_t)nt * 128 * MDIM);
    const char* B0 = (const char*)(W0T + (size_t)e * HDIM * MDIM + (size_t)nt * 128 * MDIM);
    int tid = threadIdx.x, w = tid >> 6, l = tid & 63;
    int wm = w >> 1, wn = w & 1;                   // 2M x 2N waves
    int rl = l >> 2, cch = (l & 3) * 16;           // stage lane pieces
    int fr = l & 15, fg = l >> 4;                  // frag lane pieces
    int lswz = ((fr >> 1) & 3) << 4;

    // hoisted per-lane global stage pointers (tile-0 byte addrs; rows i*64+w*16+rl)
    int r0 = 0 * 64 + w * 16 + rl, r1 = 1 * 64 + w * 16 + rl;
    const char* gA0 = A  + (size_t)r0 * MDIM * 2 + (cch ^ swzb(r0));
    const char* gA1 = A  + (size_t)r1 * MDIM * 2 + (cch ^ swzb(r1));
    const char* gG0 = Bg + (size_t)r0 * MDIM * 2 + (cch ^ swzb(r0));
    const char* gG1 = Bg + (size_t)r1 * MDIM * 2 + (cch ^ swzb(r1));
    const char* gO0 = B0 + (size_t)r0 * MDIM * 2 + (cch ^ swzb(r0));
    const char* gO1 = B0 + (size_t)r1 * MDIM * 2 + (cch ^ swzb(r1));
    int baseA = (wm * 64 + fr) * 64 + ((fg * 16) ^ lswz);
    int baseB = (wn * 64 + fr) * 64 + ((fg * 16) ^ lswz);

    f32x4 ag[4][4], ao[4][4];
    #pragma unroll
    for (int i = 0; i < 4; ++i)
        #pragma unroll
        for (int j = 0; j < 4; ++j) { ag[i][j] = (f32x4){0,0,0,0}; ao[i][j] = (f32x4){0,0,0,0}; }

    auto stage = [&](int tt) {                     // 6 gloads for tile tt
        int kk = tt * 64;
        char* dst = smem + (tt & 1) * 24576;
        gload16(gA0 + kk, dst + 0 * 4096 + w * 1024);
        gload16(gA1 + kk, dst + 1 * 4096 + w * 1024);
        gload16(gG0 + kk, dst + 8192 + 0 * 4096 + w * 1024);
        gload16(gG1 + kk, dst + 8192 + 1 * 4096 + w * 1024);
        gload16(gO0 + kk, dst + 16384 + 0 * 4096 + w * 1024);
        gload16(gO1 + kk, dst + 16384 + 1 * 4096 + w * 1024);
    };

    // prologue
    stage(0);
    asm volatile("s_waitcnt vmcnt(0)" ::: "memory");
    __builtin_amdgcn_s_barrier();

    #pragma unroll 1
    for (int t = 0; t < NK; ++t) {
        if (t + 1 < NK) stage(t + 1);
        const char* bufc = smem + (t & 1) * 24576;
        bf16x8 af[4], bg_[4], bo_[4];
        #pragma unroll
        for (int fm = 0; fm < 4; ++fm) af[fm]  = *(const bf16x8*)(bufc + baseA + fm * 1024);
        #pragma unroll
        for (int fn = 0; fn < 4; ++fn) bg_[fn] = *(const bf16x8*)(bufc + 8192  + baseB + fn * 1024);
        #pragma unroll
        for (int fn = 0; fn < 4; ++fn) bo_[fn] = *(const bf16x8*)(bufc + 16384 + baseB + fn * 1024);
        __builtin_amdgcn_s_setprio(1);
        #pragma unroll
        for (int fm = 0; fm < 4; ++fm)
            #pragma unroll
            for (int fn = 0; fn < 4; ++fn) {
                ag[fm][fn] = MFMA16(bg_[fn], af[fm], ag[fm][fn]);
                ao[fm][fn] = MFMA16(bo_[fn], af[fm], ao[fm][fn]);
            }
        __builtin_amdgcn_s_setprio(0);
        asm volatile("s_waitcnt vmcnt(0)" ::: "memory");
        __builtin_amdgcn_s_barrier();
    }

    // epilogue: silu(g)*o, packed 8B bf16 stores (4 consecutive N cols/lane)
    u16* He = Hb + (size_t)e * GC * HDIM;
    int row0 = mt * 128 + wm * 64 + fr;
    int col0 = nt * 128 + wn * 64 + fg * 4;
    #pragma unroll
    for (int fm = 0; fm < 4; ++fm)
        #pragma unroll
        for (int fn = 0; fn < 4; ++fn) {
            s16x4 pk;
            #pragma unroll
            for (int r = 0; r < 4; ++r) {
                float gv = ag[fm][fn][r], ov = ao[fm][fn][r];
                float hv = gv / (1.f + __expf(-gv)) * ov;
                pk[r] = (short)f2bf(hv);
            }
            *(s16x4*)(He + (size_t)(row0 + fm * 16) * HDIM + col0 + fn * 16) = pk;
        }
}

// ======================================================================
// GEMM3: BM=128 BN=256 BK=32, 256 threads (2Mx2N waves), wave 64x128,
// ring-2 LDS 48KB -> 2 blocks/CU. Same 2-phase body.
// LDS half: A 8KB @0, B 16KB @8192.
// ======================================================================
__global__ __launch_bounds__(256, 2) void gemm_out_v6(
        const u16* __restrict__ Hb, const u16* __restrict__ WoT,
        float* __restrict__ EO) {
    extern __shared__ char smem[];
    const int NK = HDIM / 32;                      // 128
    int bid = blockIdx.x;
    int swz = (bid & 7) * 80 + (bid >> 3);         // bijective (640 % 8 == 0)
    int mt = swz % 20, nt = (swz / 20) & 3, e = swz / 80;
    const char* A = (const char*)(Hb  + (size_t)e * GC * HDIM   + (size_t)mt * 128 * HDIM);
    const char* B = (const char*)(WoT + (size_t)e * MDIM * HDIM + (size_t)nt * 256 * HDIM);
    int tid = threadIdx.x, w = tid >> 6, l = tid & 63;
    int wm = w >> 1, wn = w & 1;
    int rl = l >> 2, cch = (l & 3) * 16;
    int fr = l & 15, fg = l >> 4;
    int lswz = ((fr >> 1) & 3) << 4;

    int r0 = 0 * 64 + w * 16 + rl, r1 = 1 * 64 + w * 16 + rl;
    int r2 = 2 * 64 + w * 16 + rl, r3 = 3 * 64 + w * 16 + rl;
    const char* gA0 = A + (size_t)r0 * HDIM * 2 + (cch ^ swzb(r0));
    const char* gA1 = A + (size_t)r1 * HDIM * 2 + (cch ^ swzb(r1));
    const char* gB0 = B + (size_t)r0 * HDIM * 2 + (cch ^ swzb(r0));
    const char* gB1 = B + (size_t)r1 * HDIM * 2 + (cch ^ swzb(r1));
    const char* gB2 = B + (size_t)r2 * HDIM * 2 + (cch ^ swzb(r2));
    const char* gB3 = B + (size_t)r3 * HDIM * 2 + (cch ^ swzb(r3));
    int baseA = (wm * 64  + fr) * 64 + ((fg * 16) ^ lswz);
    int baseB = (wn * 128 + fr) * 64 + ((fg * 16) ^ lswz);

    f32x4 acc[4][8];
    #pragma unroll
    for (int i = 0; i < 4; ++i)
        #pragma unroll
        for (int j = 0; j < 8; ++j) acc[i][j] = (f32x4){0,0,0,0};

    auto stage = [&](int tt) {                     // 6 gloads
        int kk = tt * 64;
        char* dst = smem + (tt & 1) * 24576;
        gload16(gA0 + kk, dst + 0 * 4096 + w * 1024);
        gload16(gA1 + kk, dst + 1 * 4096 + w * 1024);
        gload16(gB0 + kk, dst + 8192 + 0 * 4096 + w * 1024);
        gload16(gB1 + kk, dst + 8192 + 1 * 4096 + w * 1024);
        gload16(gB2 + kk, dst + 8192 + 2 * 4096 + w * 1024);
        gload16(gB3 + kk, dst + 8192 + 3 * 4096 + w * 1024);
    };

    stage(0);
    asm volatile("s_waitcnt vmcnt(0)" ::: "memory");
    __builtin_amdgcn_s_barrier();

    #pragma unroll 1
    for (int t = 0; t < NK; ++t) {
        if (t + 1 < NK) stage(t + 1);
        const char* bufc = smem + (t & 1) * 24576;
        bf16x8 af[4], bf[8];
        #pragma unroll
        for (int fm = 0; fm < 4; ++fm) af[fm] = *(const bf16x8*)(bufc + baseA + fm * 1024);
        #pragma unroll
        for (int fn = 0; fn < 8; ++fn) bf[fn] = *(const bf16x8*)(bufc + 8192 + baseB + fn * 1024);
        __builtin_amdgcn_s_setprio(1);
        #pragma unroll
        for (int fm = 0; fm < 4; ++fm)
            #pragma unroll
            for (int fn = 0; fn < 8; ++fn)
                acc[fm][fn] = MFMA16(bf[fn], af[fm], acc[fm][fn]);
        __builtin_amdgcn_s_setprio(0);
        asm volatile("s_waitcnt vmcnt(0)" ::: "memory");
        __builtin_amdgcn_s_barrier();
    }

    float* Ee = EO + (size_t)e * GC * MDIM;
    int row0 = mt * 128 + wm * 64 + fr;
    int col0 = nt * 256 + wn * 128 + fg * 4;
    #pragma unroll
    for (int fm = 0; fm < 4; ++fm)
        #pragma unroll
        for (int fn = 0; fn < 8; ++fn)
            *(f32x4*)(Ee + (size_t)(row0 + fm * 16) * MDIM + col0 + fn * 16) = acc[fm][fn];
}

// ---------------- combine ----------------
__global__ __launch_bounds__(256) void combine_kernel(const float* __restrict__ EO,
                                                      const int* __restrict__ top_i,
                                                      const float* __restrict__ top_p,
                                                      const int* __restrict__ token_c,
                                                      float* __restrict__ out) {
    int tok = blockIdx.x, t = threadIdx.x;
    int g = tok >> 11;
    f32x4 acc = {0.f, 0.f, 0.f, 0.f};
    #pragma unroll
    for (int k = 0; k < 2; ++k) {
        int c = token_c[tok * 2 + k];
        if (c >= 0) {
            int e = top_i[tok * 2 + k];
            float p = top_p[tok * 2 + k];
            const float* src = EO + ((size_t)e * GC + g * CAP + c) * MDIM + t * 4;
            f32x4 v = *(const f32x4*)src;
            #pragma unroll
            for (int j = 0; j < 4; ++j) acc[j] += p * v[j];
        }
    }
    *(f32x4*)(out + (size_t)tok * MDIM + t * 4) = acc;
}

extern "C" void kernel_launch(void* const* d_in, const int* in_sizes, int n_in,
                              void* d_out, int out_size, void* d_ws, size_t ws_size,
                              hipStream_t stream) {
    (void)in_sizes; (void)n_in; (void)out_size; (void)ws_size;
    const float* inputs   = (const float*)d_in[0];
    const float* paddings = (const float*)d_in[1];
    const float* router_w = (const float*)d_in[2];
    const float* wi_gate  = (const float*)d_in[3];
    const float* wi_0     = (const float*)d_in[4];
    const float* wo       = (const float*)d_in[5];
    float* out = (float*)d_out;

    char* p = (char*)d_ws;
    u16* WgT = (u16*)p; p += (size_t)E * HDIM * MDIM * 2;
    u16* W0T = (u16*)p; p += (size_t)E * HDIM * MDIM * 2;
    u16* WoT = (u16*)p; p += (size_t)E * HDIM * MDIM * 2;
    u16* Xb  = (u16*)p; p += (size_t)E * GC * MDIM * 2;
    u16* Hb  = (u16*)p; p += (size_t)E * GC * HDIM * 2;
    float* EO = (float*)p; p += (size_t)E * GC * MDIM * 4;
    int*   top_i = (int*)p;   p += (size_t)G * S * TOPK * 4;
    float* top_p = (float*)p; p += (size_t)G * S * TOPK * 4;
    int*   token_c = (int*)p; p += (size_t)G * S * TOPK * 4;
    int*   slot_token = (int*)p; p += (size_t)E * G * CAP * 4;
    float* partials = (float*)p; p += (size_t)4096 * 17 * 4;
    float* sums = (float*)p; p += 4 * 17 * 4;

    hipMemsetAsync(token_c, 0xFF, (size_t)G * S * TOPK * 4, stream);
    hipMemsetAsync(slot_token, 0xFF, (size_t)E * G * CAP * 4, stream);

    hipFuncSetAttribute((const void*)gemm_ffn12_v6,
                        hipFuncAttributeMaxDynamicSharedMemorySize, 49152);
    hipFuncSetAttribute((const void*)gemm_out_v6,
                        hipFuncAttributeMaxDynamicSharedMemorySize, 49152);

    transpose_cvt<<<dim3(HDIM/64, MDIM/64, E), 256, 0, stream>>>(wi_gate, WgT, MDIM, HDIM);
    transpose_cvt<<<dim3(HDIM/64, MDIM/64, E), 256, 0, stream>>>(wi_0,   W0T, MDIM, HDIM);
    transpose_cvt<<<dim3(MDIM/64, HDIM/64, E), 256, 0, stream>>>(wo,     WoT, HDIM, MDIM);

    router_kernel<<<G * S / 4, 256, 0, stream>>>(inputs, router_w, top_i, top_p, partials);
    reduce_partials<<<G, 256, 0, stream>>>(partials, sums);
    scan_kernel<<<G * E, 256, 0, stream>>>(top_i, paddings, slot_token, token_c);
    gather_kernel<<<E * GC, 128, 0, stream>>>(inputs, slot_token, Xb);
    gemm_ffn12_v6<<<5120, 256, 49152, stream>>>(Xb, WgT, W0T, Hb);
    gemm_out_v6<<<640, 256, 49152, stream>>>(Hb, WoT, EO);
    combine_kernel<<<G * S, 256, 0, stream>>>(EO, top_i, top_p, token_c, out);
    aux_final<<<1, 1, 0, stream>>>(sums, out);
}